// Round 3
// baseline (221.605 us; speedup 1.0000x reference)
//
#include <hip/hip_runtime.h>
#include <hip/hip_bf16.h>
#include <stdint.h>

typedef unsigned short u16;
typedef __attribute__((ext_vector_type(8))) short short8;
typedef __attribute__((ext_vector_type(16))) float f32x16;

#define B_DIM 4096
#define D_DIM 1024
#define H_DIM 1024
#define K_DIM 2048   // D + H
#define N_DIM 4096   // 4H
#define LN_EPS 1e-5f

// ---------- helpers ----------
__device__ __forceinline__ u16 f2bf(float f) {
    union { float f; uint32_t u; } v; v.f = f;
    uint32_t u = v.u;
    uint32_t r = (u + 0x7FFFu + ((u >> 16) & 1u)) >> 16;  // RNE
    return (u16)r;
}
__device__ __forceinline__ float bf2f(u16 h) {
    union { uint32_t u; float f; } v; v.u = ((uint32_t)h) << 16;
    return v.f;
}
__device__ __forceinline__ void gld16(const u16* g, u16* l) {
    __builtin_amdgcn_global_load_lds(
        (const __attribute__((address_space(1))) void*)g,
        (__attribute__((address_space(3))) void*)l,
        16, 0, 0);
}
__device__ __forceinline__ float sigm(float x) { return 1.0f / (1.0f + __expf(-x)); }
__device__ __forceinline__ float tanh_fast(float x) { return 1.0f - 2.0f / (__expf(2.0f * x) + 1.0f); }

// ---------- kernel 1: fused prep (unchanged) ----------
__global__ __launch_bounds__(256) void prep(const float* __restrict__ x,
                                            const float* __restrict__ h,
                                            const float* __restrict__ Wx,
                                            const float* __restrict__ Wh,
                                            u16* __restrict__ A,
                                            u16* __restrict__ Bt) {
    __shared__ u16 tile[64 * 64];
    const int t = threadIdx.x;
    if (blockIdx.x < 4096) {
        int id = blockIdx.x * 256 + t;
        int row = id >> 8;
        int col = (id & 255) * 8;
        const float* src = (col < D_DIM) ? (x + (size_t)row * D_DIM + col)
                                         : (h + (size_t)row * H_DIM + (col - D_DIM));
        float4 v0 = ((const float4*)src)[0];
        float4 v1 = ((const float4*)src)[1];
        union { u16 us[8]; uint4 u; } p;
        p.us[0] = f2bf(v0.x); p.us[1] = f2bf(v0.y); p.us[2] = f2bf(v0.z); p.us[3] = f2bf(v0.w);
        p.us[4] = f2bf(v1.x); p.us[5] = f2bf(v1.y); p.us[6] = f2bf(v1.z); p.us[7] = f2bf(v1.w);
        *(uint4*)(A + (size_t)id * 8) = p.u;
    } else {
        const int v = blockIdx.x - 4096;       // 0..2047 = 64 x 32
        const int n0 = (v & 63) * 64;
        const int k0 = (v >> 6) * 64;
        const int kl  = t >> 4;                // 0..15
        const int nl4 = (t & 15) * 4;          // 0..60
#pragma unroll
        for (int it = 0; it < 4; ++it) {
            const int klocal = kl + it * 16;
            const int k = k0 + klocal;
            const float* src = (k < D_DIM) ? (Wx + (size_t)k * N_DIM)
                                           : (Wh + (size_t)(k - D_DIM) * N_DIM);
            float4 w = *(const float4*)(src + n0 + nl4);
            union { u16 us[4]; uint2 u; } p;
            p.us[0] = f2bf(w.x); p.us[1] = f2bf(w.y); p.us[2] = f2bf(w.z); p.us[3] = f2bf(w.w);
            const int swz = 8 * ((klocal >> 4) & 3);
            *(uint2*)(tile + klocal * 64 + (nl4 ^ swz)) = p.u;
        }
        __syncthreads();
        const int nl = t >> 2;
        const int kp = (t & 3) * 16;
        const int swz = 8 * (t & 3);
        union { u16 us[16]; uint4 q[2]; } o;
#pragma unroll
        for (int i = 0; i < 16; ++i)
            o.us[i] = tile[(kp + i) * 64 + (nl ^ swz)];
        u16* dst = Bt + (size_t)(n0 + nl) * K_DIM + k0 + kp;
        *(uint4*)dst = o.q[0];
        *(uint4*)(dst + 8) = o.q[1];
    }
}

// ---------- kernel 2: GEMM a = A @ Bt^T + bias -> bf16 [4096][4096] ----------
// 256x256 block, 8 waves (2M x 4N), per-wave 128x64 (acc[4][2] of 32x32x16).
// 4-slot half-tile ring per matrix: slot s = region % 4, region r = (t,ks) =
// (r>>1, r&1). Region q stages region q+3's data into slot (q+3)%4.
//
// 2-barrier region (m201 placement: issue pre-barrier, consume post-barrier):
//   { read bf(q+1) -> alt regs        (hidden: consumed next region)
//     stage(q+3)                      (4x gld16, in flight across barriers)
//     s_waitcnt vmcnt(4)              (forces stages of q-1 and older landed)
//     BARRIER_A
//     read af(q)                      (pipelined under MFMA via compiler lgkm)
//     setprio(1) ; 16 MFMA ; setprio(0)
//     BARRIER_B }
// Hazards: reads(q) slot staged q-3 (landed by vmcnt@q-1 + BARRIER_A(q-1));
// stage(q) overwrites slot (q-1)%4, whose af-reads were consumed by MFMA(q-1)
// before BARRIER_B(q-1). vmcnt never 0 in the loop. Tail stages clamp tile
// index (&31) -> valid reads, data never consumed.
__global__ __launch_bounds__(512, 2) void gemm_bf16(const u16* __restrict__ A,   // [4096][2048]
                                                    const u16* __restrict__ Bt,  // [4096][2048]
                                                    const float* __restrict__ bias,
                                                    u16* __restrict__ C) {       // [4096][4096]
    __shared__ u16 As[4][8192];   // [slot][row*32 + swizzled 16B-block]
    __shared__ u16 Bs[4][8192];
    const int tid = threadIdx.x;
    const int wave = tid >> 6, lane = tid & 63;

    // bijective XCD swizzle (256 wgs % 8 == 0)
    const int bid = blockIdx.y * 16 + blockIdx.x;
    const int swz_bid = (bid & 7) * 32 + (bid >> 3);
    const int m0 = (swz_bid >> 4) * 256;
    const int n0 = (swz_bid & 15) * 256;

    const int wm = (wave & 1) * 128;     // 2 waves along M
    const int wn = (wave >> 1) * 64;     // 4 waves along N
    const int lr = lane & 31, half = lane >> 5;

    // ---- staging constants (same verified swizzle as r2) ----
    // dest (linear): row = pass*128 + wave*16 + (lane>>2), 16B-block = lane&3
    // src 16B-block = (lane&3) ^ ((row>>1)&3) = (lane&3) ^ ((lane>>3)&3)
    const int srow = wave * 16 + (lane >> 2);
    const int qsrc = (lane & 3) ^ ((lane >> 3) & 3);
    const u16* Asrc = A  + (size_t)(m0 + srow) * K_DIM + qsrc * 8;
    const u16* Bsrc = Bt + (size_t)(n0 + srow) * K_DIM + qsrc * 8;
    const int ldst = wave * 512;   // u16; + pass*4096

    auto stage_slot = [&](int slot, int rho) {
        const int tt = (rho >> 1) & 31;   // clamp for tail regions
        const int ks = rho & 1;
        const int ko = tt * 64 + ks * 32;
        gld16(Asrc + ko,                       &As[slot][ldst]);
        gld16(Asrc + ko + (size_t)128 * K_DIM, &As[slot][ldst + 4096]);
        gld16(Bsrc + ko,                       &Bs[slot][ldst]);
        gld16(Bsrc + ko + (size_t)128 * K_DIM, &Bs[slot][ldst + 4096]);
    };

    // ---- fragment read constants ----
    const int sA = (lr >> 1) & 3;        // row-bits 1..2 == lr bits 1..2
    const int aoff = (wm + lr) * 32;
    const int boff = (wn + lr) * 32;

    f32x16 acc[4][2] = {};
    short8 af[2][4], bfA[2][2], bfB[2][2];

#define RD_B(DST, SLOT)                                                           \
    _Pragma("unroll")                                                             \
    for (int kk = 0; kk < 2; ++kk)                                                \
        _Pragma("unroll")                                                         \
        for (int qj = 0; qj < 2; ++qj)                                            \
            DST[kk][qj] = *(const short8*)(                                       \
                &Bs[SLOT][boff + qj * 1024 + (((kk * 2 + half) ^ sA) << 3)]);

#define REGION(SLOT, BFC, BFN, NSLOT, RHO)                                        \
    {                                                                             \
        RD_B(BFN, NSLOT);                                                         \
        stage_slot((RHO) & 3, RHO);                                               \
        asm volatile("s_waitcnt vmcnt(4)" ::: "memory");                          \
        __builtin_amdgcn_s_barrier();                                             \
        _Pragma("unroll")                                                         \
        for (int kk = 0; kk < 2; ++kk)                                            \
            _Pragma("unroll")                                                     \
            for (int i = 0; i < 4; ++i)                                           \
                af[kk][i] = *(const short8*)(                                     \
                    &As[SLOT][aoff + i * 1024 + (((kk * 2 + half) ^ sA) << 3)]);  \
        __builtin_amdgcn_s_setprio(1);                                            \
        _Pragma("unroll")                                                         \
        for (int kk = 0; kk < 2; ++kk)                                            \
            _Pragma("unroll")                                                     \
            for (int i = 0; i < 4; ++i)                                           \
                _Pragma("unroll")                                                 \
                for (int qj = 0; qj < 2; ++qj)                                    \
                    acc[i][qj] = __builtin_amdgcn_mfma_f32_32x32x16_bf16(         \
                        af[kk][i], BFC[kk][qj], acc[i][qj], 0, 0, 0);             \
        __builtin_amdgcn_s_setprio(0);                                            \
        __builtin_amdgcn_s_barrier();                                             \
        asm volatile("" ::: "memory");                                            \
    }

    // prologue: stage regions 0,1,2 into slots 0,1,2; drain; read bf(region 0)
    stage_slot(0, 0); stage_slot(1, 1); stage_slot(2, 2);
    asm volatile("s_waitcnt vmcnt(0)" ::: "memory");
    __builtin_amdgcn_s_barrier();
    asm volatile("" ::: "memory");
    RD_B(bfA, 0);

    // 64 regions = 32 K-tiles; 4 regions per iteration, slots 0..3 statically
    for (int it = 0; it < 16; ++it) {
        const int q0 = it * 4;
        REGION(0, bfA, bfB, 1, q0 + 3);
        REGION(1, bfB, bfA, 2, q0 + 4);
        REGION(2, bfA, bfB, 3, q0 + 5);
        REGION(3, bfB, bfA, 0, q0 + 6);
    }
#undef REGION
#undef RD_B

    // epilogue: 32x32 C/D layout col=lane&31, row=(reg&3)+8*(reg>>2)+4*(lane>>5)
#pragma unroll
    for (int i = 0; i < 4; ++i) {
#pragma unroll
        for (int j = 0; j < 2; ++j) {
            const int c = n0 + wn + 32 * j + lr;
            const float bb = bias[c];
#pragma unroll
            for (int reg = 0; reg < 16; ++reg) {
                const int row = m0 + wm + 32 * i + (reg & 3) + 8 * (reg >> 2) + 4 * half;
                C[(size_t)row * N_DIM + c] = f2bf(acc[i][j][reg] + bb);
            }
        }
    }
}

// ---------- kernel 3: LayerNorm + gates + cell update (unchanged) ----------
__global__ __launch_bounds__(256) void ln_lstm(const u16* __restrict__ aT,     // [4096][4096] bf16
                                               const float* __restrict__ pc,   // prev_c
                                               const float* __restrict__ gamma,
                                               const float* __restrict__ beta,
                                               float* __restrict__ out) {      // [h | c]
    const int row = blockIdx.x;
    const int t = threadIdx.x;
    const u16* ar = aT + (size_t)row * N_DIM;
    const int j0 = t * 4;

    union U2 { uint2 u; u16 us[4]; };
    U2 g4[4];
#pragma unroll
    for (int s = 0; s < 4; ++s) g4[s].u = *(const uint2*)(ar + s * H_DIM + j0);

    float sum = 0.f, ssq = 0.f;
#pragma unroll
    for (int s = 0; s < 4; ++s)
#pragma unroll
        for (int e = 0; e < 4; ++e) { float v = bf2f(g4[s].us[e]); sum += v; ssq += v * v; }

#pragma unroll
    for (int off = 32; off > 0; off >>= 1) {
        sum += __shfl_down(sum, off, 64);
        ssq += __shfl_down(ssq, off, 64);
    }
    __shared__ float red[8];
    if ((t & 63) == 0) { red[t >> 6] = sum; red[4 + (t >> 6)] = ssq; }
    __syncthreads();
    const float ts = red[0] + red[1] + red[2] + red[3];
    const float tq = red[4] + red[5] + red[6] + red[7];
    const float mu = ts * (1.0f / N_DIM);
    const float var = fmaxf(tq * (1.0f / N_DIM) - mu * mu, 0.0f);
    const float rs = rsqrtf(var + LN_EPS);

    float vi[4], vf[4], vo[4], vg[4];
    auto gate = [&](int s, float* v) {
        const int off = s * H_DIM;
        float4 gm = *(const float4*)(gamma + off + j0);
        float4 bt = *(const float4*)(beta + off + j0);
        v[0] = (bf2f(g4[s].us[0]) - mu) * rs * gm.x + bt.x;
        v[1] = (bf2f(g4[s].us[1]) - mu) * rs * gm.y + bt.y;
        v[2] = (bf2f(g4[s].us[2]) - mu) * rs * gm.z + bt.z;
        v[3] = (bf2f(g4[s].us[3]) - mu) * rs * gm.w + bt.w;
    };
    gate(0, vi); gate(1, vf); gate(2, vo); gate(3, vg);

    float4 c4 = *(const float4*)(pc + (size_t)row * H_DIM + j0);
    float cin[4] = {c4.x, c4.y, c4.z, c4.w};
    float nh[4], nc[4];
#pragma unroll
    for (int r = 0; r < 4; ++r) {
        float ig = sigm(vi[r]);
        float fg = sigm(vf[r]);
        float og = sigm(vo[r]);
        float gg = tanh_fast(vg[r]);
        nc[r] = fg * cin[r] + ig * gg;
        nh[r] = og * tanh_fast(nc[r]);
    }
    float4 h4 = {nh[0], nh[1], nh[2], nh[3]};
    float4 c4o = {nc[0], nc[1], nc[2], nc[3]};
    *(float4*)(out + (size_t)row * H_DIM + j0) = h4;
    *(float4*)(out + (size_t)B_DIM * H_DIM + (size_t)row * H_DIM + j0) = c4o;
}

// ---------- launch ----------
extern "C" void kernel_launch(void* const* d_in, const int* in_sizes, int n_in,
                              void* d_out, int out_size, void* d_ws, size_t ws_size,
                              hipStream_t stream) {
    const float* x  = (const float*)d_in[0];
    const float* ph = (const float*)d_in[1];
    const float* pc = (const float*)d_in[2];
    const float* Wx = (const float*)d_in[3];
    const float* Wh = (const float*)d_in[4];
    const float* b  = (const float*)d_in[5];
    const float* gm = (const float*)d_in[6];
    const float* bt = (const float*)d_in[7];
    float* out = (float*)d_out;

    char* ws = (char*)d_ws;
    u16* Abf = (u16*)ws;                               // 16 MiB: [4096][2048] bf16
    u16* Btb = (u16*)(ws + (size_t)16 * 1024 * 1024);  // 16 MiB: [4096][2048] bf16
    u16* aT  = (u16*)(ws + (size_t)32 * 1024 * 1024);  // 32 MiB: [4096][4096] bf16

    prep<<<dim3(4096 + 2048), dim3(256), 0, stream>>>(x, ph, Wx, Wh, Abf, Btb);
    gemm_bf16<<<dim3(16, 16), dim3(512), 0, stream>>>(Abf, Btb, b, aT);
    ln_lstm<<<dim3(4096), dim3(256), 0, stream>>>(aT, pc, gm, bt, out);
}